// Round 5
// baseline (391.285 us; speedup 1.0000x reference)
//
#include <hip/hip_runtime.h>
#include <hip/hip_bf16.h>

#define NN 1024
#define IN_CH 128
#define EDGE_CH 32
#define OUT_CH 128
#define NNSQ ((size_t)NN * (size_t)NN)

typedef __attribute__((ext_vector_type(8))) short bf16x8;
typedef __attribute__((ext_vector_type(4))) float f32x4;

// round-to-nearest-even float -> bf16 (bit trick)
static __device__ __forceinline__ short f2bf(float f) {
    union { float f; unsigned u; } v; v.f = f;
    unsigned r = v.u + 0x7FFFu + ((v.u >> 16) & 1u);
    return (short)(r >> 16);
}

// ---------------------------------------------------------------------------
// Kernel A: P = node_mat @ node_weight (stored TRANSPOSED, bf16: PT[o][m]),
//           R = node_mat @ root (fp32).  (unchanged)
// ---------------------------------------------------------------------------
__global__ void node_gemm_kernel(const float* __restrict__ node_mat,
                                 const float* __restrict__ node_weight,
                                 const float* __restrict__ root,
                                 short* __restrict__ PT,
                                 float* __restrict__ R) {
    __shared__ float nm[2 * IN_CH];
    int tid = threadIdx.x;
    int n0 = blockIdx.x * 2;
    nm[tid] = node_mat[n0 * IN_CH + tid];
    __syncthreads();
    int o = tid & 127;
    int h = tid >> 7;
    const float* nr = &nm[h * IN_CH];
    float accp = 0.f, accr = 0.f;
#pragma unroll 8
    for (int c = 0; c < IN_CH; ++c) {
        float x = nr[c];
        accp += x * node_weight[c * OUT_CH + o];
        accr += x * root[c * OUT_CH + o];
    }
    R[(size_t)(n0 + h) * OUT_CH + o] = accr;
    PT[(size_t)o * NN + (n0 + h)] = f2bf(accp);  // transposed bf16 store
}

// ---------------------------------------------------------------------------
// Kernel C (runs SECOND now): out = adj @ P + R + bias  (WRITE mode).
// grid 128 = 64 n-tiles (16 rows) x 2 o-halves (64 cols); waves split K=1024
// into 4 x 256, reduce through padded LDS, coalesced write.
// edge halves atomicAdd their e_compress partials on top afterwards.
// ---------------------------------------------------------------------------
__global__ void adjp_kernel(const float* __restrict__ adj,
                            const short* __restrict__ PT,
                            const float* __restrict__ R,
                            const float* __restrict__ bias,
                            float* __restrict__ out) {
    int blk = blockIdx.x;
    int nb = blk & 63;          // n-tile: 16 rows
    int oh = blk >> 6;          // o-half: 64 cols
    int tid = threadIdx.x;
    int wave = tid >> 6;
    int lane = tid & 63;
    int quad = lane >> 4;
    int col  = lane & 15;
    int n0 = nb * 16;
    int o0 = oh * 64;

    f32x4 acc[4];
#pragma unroll
    for (int ot = 0; ot < 4; ++ot) acc[ot] = (f32x4){0.f, 0.f, 0.f, 0.f};

    int kbase = wave * 256;     // wave-level K-split, reduced in LDS below
#pragma unroll
    for (int ks = 0; ks < 8; ++ks) {
        int k = kbase + ks * 32 + quad * 8;
        const float* ap = adj + (size_t)(n0 + col) * NN + k;
        f32x4 a0 = *(const f32x4*)ap;
        f32x4 a1 = *(const f32x4*)(ap + 4);
        bf16x8 a;
#pragma unroll
        for (int j = 0; j < 4; ++j) { a[j] = f2bf(a0[j]); a[4 + j] = f2bf(a1[j]); }
#pragma unroll
        for (int ot = 0; ot < 4; ++ot) {
            int o = o0 + ot * 16 + col;
            bf16x8 b = *(const bf16x8*)(PT + (size_t)o * NN + k);
            acc[ot] = __builtin_amdgcn_mfma_f32_16x16x32_bf16(a, b, acc[ot], 0, 0, 0);
        }
    }

    // cross-wave K-reduction through LDS (pad 64->65: quads land on distinct banks)
    __shared__ float red[4][16][65];
#pragma unroll
    for (int ot = 0; ot < 4; ++ot)
#pragma unroll
        for (int r = 0; r < 4; ++r)
            red[wave][quad * 4 + r][ot * 16 + col] = acc[ot][r];
    __syncthreads();

    // 1024 tile elements / 256 threads = 4 each; coalesced write (out = v+R+bias)
#pragma unroll
    for (int i = tid; i < 16 * 64; i += 256) {
        int rr = i >> 6;
        int cc = i & 63;
        float v = red[0][rr][cc] + red[1][rr][cc] + red[2][rr][cc] + red[3][rr][cc];
        size_t idx = (size_t)(n0 + rr) * OUT_CH + o0 + cc;
        out[idx] = v + R[idx] + bias[o0 + cc];
    }
}

// ---------------------------------------------------------------------------
// Kernel B v4 (heavy): per (n, half), partial over m in [half*512, half*512+512):
//   Gp[b] = sum_m adj[n,m] * relu( sum_e edge_adj[e,n,m] * L1[e,b] )
//   atomicAdd(out[n,o], sum_{b<127} Gp[b]*L2[b,o])   (out pre-filled by adjp)
//
// v2 post-mortem: latency-bound (1 TB/s, MfmaUtil 3.8%), grid 1024 = only
// 4 blocks/CU (grid cap). v3 post-mortem: runtime-indexed f32x4 st[2][4]
// spilled to scratch (270 MB TCC writes) -- rule #20.
// v4: v2's proven lockstep pipeline, but
//   - grid 2048 (n split in 2 m-halves) + 14 KB LDS -> 8 blocks/CU,
//   - chunk = 64 m (8 chunks of 32e x 64m = 8 KB),
//   - 2-deep prefetch with HAND-NAMED regs stA0/stA1/stB0/stB1, even/odd
//     double body -> all register indices compile-time static, no scratch.
// Staging: thread t: e = t>>3, m-off = (t&7)*4 and +32; per wave-instr
// 8 e-rows x 128 B contiguous. LDS transposed [m][40 shorts] (80-B rows).
// MFMA 16x16x32 bf16: A-frag = L1^T [b=bt*16+col][e=quad*8+j] (constant);
// B-frag = one ds_read_b128 [e=quad*8+j][m]; D row=quad*4+r (b), col=m.
// ---------------------------------------------------------------------------
__global__ void edge_out_kernel(const float* __restrict__ edge_adj,
                                const float* __restrict__ adj,
                                const float* __restrict__ L1,
                                const float* __restrict__ L2,
                                float* __restrict__ out) {
    int n    = blockIdx.x >> 1;
    int half = blockIdx.x & 1;
    int tid = threadIdx.x;
    int wave = tid >> 6;
    int lane = tid & 63;
    int quad = lane >> 4;
    int col  = lane & 15;

    // double-buffered transposed chunk: [64 m][40 shorts] = 5120 B each
    __shared__ __attribute__((aligned(16))) short ea_lds[2][64 * 40];  // 10 KB
    __shared__ float gred[4][OUT_CH];
    __shared__ float gs[OUT_CH];
    __shared__ float part[2][OUT_CH];

    // Preload constant A fragments: 8 b-tiles of L1^T [b=bt*16+col][e=quad*8+j]
    bf16x8 a_frag[8];
#pragma unroll
    for (int bt = 0; bt < 8; ++bt) {
        int b = bt * 16 + col;
#pragma unroll
        for (int j = 0; j < 8; ++j) {
            int e = quad * 8 + j;
            float v = (b < OUT_CH - 1) ? L1[e * (OUT_CH - 1) + b] : 0.0f;  // pad b=127
            a_frag[bt][j] = f2bf(v);
        }
    }

    float g_acc[8][4];
#pragma unroll
    for (int bt = 0; bt < 8; ++bt)
#pragma unroll
        for (int r = 0; r < 4; ++r) g_acc[bt][r] = 0.0f;

    int mbase = half * 512;
    const float* adj_row = adj + (size_t)n * NN + mbase;

    // staging mapping: thread t covers e = t>>3, m-offsets (t&7)*4 and +32
    int se = tid >> 3;                       // 0..31
    int sm = (tid & 7) * 4;                  // 0..28
    const float* ea_t = edge_adj + (size_t)se * NNSQ + (size_t)n * NN + mbase + sm;

    short* buf0 = &ea_lds[0][0];
    short* buf1 = &ea_lds[1][0];

    f32x4 stA0, stA1, stB0, stB1;            // named: never scratch (v3 lesson)

#define LOAD_A(CH) { stA0 = *(const f32x4*)(ea_t + (CH) * 64); \
                     stA1 = *(const f32x4*)(ea_t + (CH) * 64 + 32); }
#define LOAD_B(CH) { stB0 = *(const f32x4*)(ea_t + (CH) * 64); \
                     stB1 = *(const f32x4*)(ea_t + (CH) * 64 + 32); }
#define CONVERT(S0, S1, BUF) { \
        _Pragma("unroll") for (int k = 0; k < 4; ++k) { \
            (BUF)[(sm + k) * 40 + se]      = f2bf((S0)[k]); \
            (BUF)[(sm + 32 + k) * 40 + se] = f2bf((S1)[k]); } }
#define COMPUTE(BUF, CH) { \
        int mloc = wave * 16 + col; \
        float adjv = adj_row[(CH) * 64 + mloc]; \
        bf16x8 bfv = *(const bf16x8*)((BUF) + mloc * 40 + quad * 8); \
        _Pragma("unroll") for (int bt = 0; bt < 8; ++bt) { \
            f32x4 d = __builtin_amdgcn_mfma_f32_16x16x32_bf16( \
                a_frag[bt], bfv, (f32x4){0.f, 0.f, 0.f, 0.f}, 0, 0, 0); \
            _Pragma("unroll") for (int r = 0; r < 4; ++r) \
                g_acc[bt][r] += fmaxf(d[r], 0.0f) * adjv; } }

    // prologue: chunks 0 (stA) and 1 (stB) in flight; convert 0; publish
    LOAD_A(0);
    LOAD_B(1);
    CONVERT(stA0, stA1, buf0);
    __syncthreads();

    for (int cc = 0; cc < 4; ++cc) {
        int c0 = cc * 2;
        // even step: compute chunk c0 from buf0; chunk c0+1 arrives in stB
        if (c0 + 2 < 8) LOAD_A(c0 + 2);
        COMPUTE(buf0, c0);
        CONVERT(stB0, stB1, buf1);           // chunk c0+1 -> buf1
        __syncthreads();
        // odd step: compute chunk c0+1 from buf1; chunk c0+2 arrives in stA
        if (c0 + 3 < 8) LOAD_B(c0 + 3);
        COMPUTE(buf1, c0 + 1);
        if (c0 + 2 < 8) CONVERT(stA0, stA1, buf0);  // chunk c0+2 -> buf0
        __syncthreads();
    }
#undef LOAD_A
#undef LOAD_B
#undef CONVERT
#undef COMPUTE

    // reduce over the 16 column-lanes of each quad (sum over this lane's m's)
#pragma unroll
    for (int bt = 0; bt < 8; ++bt)
#pragma unroll
        for (int r = 0; r < 4; ++r) {
            float v = g_acc[bt][r];
            v += __shfl_xor(v, 1);
            v += __shfl_xor(v, 2);
            v += __shfl_xor(v, 4);
            v += __shfl_xor(v, 8);
            g_acc[bt][r] = v;
        }

    if (col == 0) {
#pragma unroll
        for (int bt = 0; bt < 8; ++bt)
#pragma unroll
            for (int r = 0; r < 4; ++r)
                gred[wave][bt * 16 + quad * 4 + r] = g_acc[bt][r];
    }
    __syncthreads();
    if (tid < OUT_CH)
        gs[tid] = gred[0][tid] + gred[1][tid] + gred[2][tid] + gred[3][tid];
    __syncthreads();

    // partial epilogue: atomicAdd(out[n,o], sum_{b<127} gs[b]*L2[b,o])
    int o = tid & 127;
    int hf = tid >> 7;
    float acc = 0.f;
    int blo = hf * 64, bhi = hf ? 127 : 64;
#pragma unroll 8
    for (int b = blo; b < bhi; ++b)
        acc += gs[b] * L2[b * OUT_CH + o];   // gs[b] is an LDS broadcast (free)
    part[hf][o] = acc;
    __syncthreads();
    if (tid < 128)
        atomicAdd(&out[(size_t)n * OUT_CH + tid], part[0][tid] + part[1][tid]);
}

extern "C" void kernel_launch(void* const* d_in, const int* in_sizes, int n_in,
                              void* d_out, int out_size, void* d_ws, size_t ws_size,
                              hipStream_t stream) {
    const float* node_mat    = (const float*)d_in[0];
    const float* adj         = (const float*)d_in[1];
    const float* edge_adj    = (const float*)d_in[2];
    const float* node_weight = (const float*)d_in[3];
    const float* edge_lay_1  = (const float*)d_in[4];
    const float* edge_lay_2  = (const float*)d_in[5];
    const float* root        = (const float*)d_in[6];
    const float* bias        = (const float*)d_in[7];
    float* out = (float*)d_out;

    short* PT = (short*)d_ws;                       // 128*1024 bf16 = 256 KB
    float* R  = (float*)((char*)d_ws + OUT_CH * NN * sizeof(short));  // 512 KB

    node_gemm_kernel<<<NN / 2, 256, 0, stream>>>(node_mat, node_weight, root, PT, R);
    adjp_kernel<<<128, 256, 0, stream>>>(adj, PT, R, bias, out);   // writes base
    edge_out_kernel<<<2 * NN, 256, 0, stream>>>(edge_adj, adj, edge_lay_1,
                                                edge_lay_2, out);  // atomic +=
}

// Round 6
// 273.963 us; speedup vs baseline: 1.4282x; 1.4282x over previous
//
#include <hip/hip_runtime.h>
#include <hip/hip_bf16.h>

#define NN 1024
#define IN_CH 128
#define EDGE_CH 32
#define OUT_CH 128
#define NNSQ ((size_t)NN * (size_t)NN)

typedef __attribute__((ext_vector_type(8))) short bf16x8;
typedef __attribute__((ext_vector_type(4))) float f32x4;

// round-to-nearest-even float -> bf16 (bit trick)
static __device__ __forceinline__ short f2bf(float f) {
    union { float f; unsigned u; } v; v.f = f;
    unsigned r = v.u + 0x7FFFu + ((v.u >> 16) & 1u);
    return (short)(r >> 16);
}

// ---------------------------------------------------------------------------
// Kernel A: P = node_mat @ node_weight (stored TRANSPOSED, bf16: PT[o][m]),
//           R = node_mat @ root (fp32).  (unchanged)
// ---------------------------------------------------------------------------
__global__ void node_gemm_kernel(const float* __restrict__ node_mat,
                                 const float* __restrict__ node_weight,
                                 const float* __restrict__ root,
                                 short* __restrict__ PT,
                                 float* __restrict__ R) {
    __shared__ float nm[2 * IN_CH];
    int tid = threadIdx.x;
    int n0 = blockIdx.x * 2;
    nm[tid] = node_mat[n0 * IN_CH + tid];
    __syncthreads();
    int o = tid & 127;
    int h = tid >> 7;
    const float* nr = &nm[h * IN_CH];
    float accp = 0.f, accr = 0.f;
#pragma unroll 8
    for (int c = 0; c < IN_CH; ++c) {
        float x = nr[c];
        accp += x * node_weight[c * OUT_CH + o];
        accr += x * root[c * OUT_CH + o];
    }
    R[(size_t)(n0 + h) * OUT_CH + o] = accr;
    PT[(size_t)o * NN + (n0 + h)] = f2bf(accp);  // transposed bf16 store
}

// ---------------------------------------------------------------------------
// Kernel C (runs before edge_out): out = adj @ P + R + bias  (WRITE mode).
// grid 128 = 64 n-tiles x 2 o-halves; waves split K=1024 into 4 x 256,
// reduce through padded LDS, coalesced write. (unchanged from v4)
// ---------------------------------------------------------------------------
__global__ void adjp_kernel(const float* __restrict__ adj,
                            const short* __restrict__ PT,
                            const float* __restrict__ R,
                            const float* __restrict__ bias,
                            float* __restrict__ out) {
    int blk = blockIdx.x;
    int nb = blk & 63;          // n-tile: 16 rows
    int oh = blk >> 6;          // o-half: 64 cols
    int tid = threadIdx.x;
    int wave = tid >> 6;
    int lane = tid & 63;
    int quad = lane >> 4;
    int col  = lane & 15;
    int n0 = nb * 16;
    int o0 = oh * 64;

    f32x4 acc[4];
#pragma unroll
    for (int ot = 0; ot < 4; ++ot) acc[ot] = (f32x4){0.f, 0.f, 0.f, 0.f};

    int kbase = wave * 256;     // wave-level K-split, reduced in LDS below
#pragma unroll
    for (int ks = 0; ks < 8; ++ks) {
        int k = kbase + ks * 32 + quad * 8;
        const float* ap = adj + (size_t)(n0 + col) * NN + k;
        f32x4 a0 = *(const f32x4*)ap;
        f32x4 a1 = *(const f32x4*)(ap + 4);
        bf16x8 a;
#pragma unroll
        for (int j = 0; j < 4; ++j) { a[j] = f2bf(a0[j]); a[4 + j] = f2bf(a1[j]); }
#pragma unroll
        for (int ot = 0; ot < 4; ++ot) {
            int o = o0 + ot * 16 + col;
            bf16x8 b = *(const bf16x8*)(PT + (size_t)o * NN + k);
            acc[ot] = __builtin_amdgcn_mfma_f32_16x16x32_bf16(a, b, acc[ot], 0, 0, 0);
        }
    }

    __shared__ float red[4][16][65];
#pragma unroll
    for (int ot = 0; ot < 4; ++ot)
#pragma unroll
        for (int r = 0; r < 4; ++r)
            red[wave][quad * 4 + r][ot * 16 + col] = acc[ot][r];
    __syncthreads();

#pragma unroll
    for (int i = tid; i < 16 * 64; i += 256) {
        int rr = i >> 6;
        int cc = i & 63;
        float v = red[0][rr][cc] + red[1][rr][cc] + red[2][rr][cc] + red[3][rr][cc];
        size_t idx = (size_t)(n0 + rr) * OUT_CH + o0 + cc;
        out[idx] = v + R[idx] + bias[o0 + cc];
    }
}

// ---------------------------------------------------------------------------
// Kernel B v5 (heavy): per node n,
//   G[b]  = sum_m adj[n,m] * relu( sum_e edge_adj[e,n,m] * L1[e,b] )
//   out[n,o] += sum_{b<127} G[b]*L2[b,o]            (base pre-written by adjp)
//
// v2/v4 post-mortems: (a) register pressure (a_frag 32 + g_acc 32 + staging)
// spilled to scratch (v4: 408 MB TCC writes); (b) all staging reads had
// 4-MiB e-stride with only 256 B m-extent per instant -> every concurrent
// request aliases the same HBM channel + L2 set -> ~1 TB/s ceiling.
// v5:
//   - b-SPLIT across waves: wave w owns b-tiles {2w, 2w+1}, FULL m-range.
//     a_frag 2x4=8 VGPRs, g_acc 2x4=8 VGPRs, staging 8x4=32 -> ~65 total,
//     no spill.
//   - staging: one instruction = ONE e-plane x 1 KB contiguous m
//     (64 lanes x float4) -> 4+ channels/instr. Chunk = 256 m x 32 e;
//     wave w loads e = 8w..8w+7 (8 instrs). Lane then holds an 8e x 4m
//     register block -> LDS transpose is register re-indexing:
//     4x ds_write_b128 to rows [m][e0..e7 at w*16B]. Rows padded to 80 B.
//   - chunk order rotated by n&3 -> concurrent blocks hit different
//     m-phases -> channel spread across the grid.
//   - double-buffered 40 KB LDS, 1 barrier/chunk, 1-deep prefetch.
// MFMA 16x16x32 bf16: A-frag = L1^T [b=bt*16+col][e=quad*8+j] (constant);
// B-frag = one ds_read_b128 [m=st*16+col][e=quad*8+j]; D row=quad*4+r (b).
// ---------------------------------------------------------------------------
__global__ void edge_out_kernel(const float* __restrict__ edge_adj,
                                const float* __restrict__ adj,
                                const float* __restrict__ L1,
                                const float* __restrict__ L2,
                                float* __restrict__ out) {
    int n = blockIdx.x;
    int tid = threadIdx.x;
    int wave = tid >> 6;
    int lane = tid & 63;
    int quad = lane >> 4;
    int col  = lane & 15;

    // double-buffered transposed chunk: [256 m][40 shorts] = 20 KB each
    __shared__ __attribute__((aligned(16))) short ea_lds[2][256 * 40];  // 40 KB
    __shared__ float adj_lds[NN];                                       // 4 KB
    __shared__ float gs[OUT_CH];
    __shared__ float part[2][OUT_CH];

    // stage the adj row once (coalesced, 4 KB)
    *(f32x4*)&adj_lds[tid * 4] = *(const f32x4*)(adj + (size_t)n * NN + tid * 4);

    // A fragments: this wave's two b-tiles of L1^T [b][e=quad*8+j]
    bf16x8 a_frag0, a_frag1;
#pragma unroll
    for (int j = 0; j < 8; ++j) {
        int e = quad * 8 + j;
        int b0 = (wave * 2 + 0) * 16 + col;
        int b1 = (wave * 2 + 1) * 16 + col;
        a_frag0[j] = f2bf((b0 < OUT_CH - 1) ? L1[e * (OUT_CH - 1) + b0] : 0.0f);
        a_frag1[j] = f2bf((b1 < OUT_CH - 1) ? L1[e * (OUT_CH - 1) + b1] : 0.0f);
    }

    float g0[4] = {0.f, 0.f, 0.f, 0.f};
    float g1[4] = {0.f, 0.f, 0.f, 0.f};

    // staging base: this wave's 8 e-planes, this n's row, lane covers 4 m
    const float* ea_b = edge_adj + (size_t)(wave * 8) * NNSQ + (size_t)n * NN + lane * 4;

    f32x4 st0, st1, st2, st3, st4, st5, st6, st7;   // named: never scratch

#define ISSUE(AC) { \
        const float* p_ = ea_b + (AC) * 256; \
        st0 = *(const f32x4*)(p_ + 0 * NNSQ); st1 = *(const f32x4*)(p_ + 1 * NNSQ); \
        st2 = *(const f32x4*)(p_ + 2 * NNSQ); st3 = *(const f32x4*)(p_ + 3 * NNSQ); \
        st4 = *(const f32x4*)(p_ + 4 * NNSQ); st5 = *(const f32x4*)(p_ + 5 * NNSQ); \
        st6 = *(const f32x4*)(p_ + 6 * NNSQ); st7 = *(const f32x4*)(p_ + 7 * NNSQ); }
// lane holds 8e x 4m block; write 4 rows of 8 bf16 (16 B) = 4x ds_write_b128
#define CONVERT(BUF) { \
        _Pragma("unroll") for (int k = 0; k < 4; ++k) { \
            bf16x8 pk_; \
            pk_[0] = f2bf(st0[k]); pk_[1] = f2bf(st1[k]); \
            pk_[2] = f2bf(st2[k]); pk_[3] = f2bf(st3[k]); \
            pk_[4] = f2bf(st4[k]); pk_[5] = f2bf(st5[k]); \
            pk_[6] = f2bf(st6[k]); pk_[7] = f2bf(st7[k]); \
            *(bf16x8*)((BUF) + (lane * 4 + k) * 40 + wave * 8) = pk_; } }
#define COMPUTE(BUF, AC) { \
        _Pragma("unroll") for (int st = 0; st < 16; ++st) { \
            int mrow = st * 16 + col; \
            float adjv = adj_lds[(AC) * 256 + mrow]; \
            bf16x8 bfv = *(const bf16x8*)((BUF) + mrow * 40 + quad * 8); \
            f32x4 d0 = __builtin_amdgcn_mfma_f32_16x16x32_bf16( \
                a_frag0, bfv, (f32x4){0.f, 0.f, 0.f, 0.f}, 0, 0, 0); \
            f32x4 d1 = __builtin_amdgcn_mfma_f32_16x16x32_bf16( \
                a_frag1, bfv, (f32x4){0.f, 0.f, 0.f, 0.f}, 0, 0, 0); \
            _Pragma("unroll") for (int r = 0; r < 4; ++r) { \
                g0[r] += fmaxf(d0[r], 0.0f) * adjv; \
                g1[r] += fmaxf(d1[r], 0.0f) * adjv; } } }

    // prologue: stage chunk (n&3) into lds[0]
    ISSUE(n & 3);
    CONVERT(&ea_lds[0][0]);
    __syncthreads();

#pragma unroll
    for (int c = 0; c < 4; ++c) {
        short* bufc = &ea_lds[c & 1][0];
        short* bufn = &ea_lds[(c & 1) ^ 1][0];
        if (c < 3) ISSUE((n + c + 1) & 3);     // prefetch next chunk
        COMPUTE(bufc, (n + c) & 3);
        if (c < 3) CONVERT(bufn);              // waits loads, writes other buffer
        __syncthreads();
    }
#undef ISSUE
#undef CONVERT
#undef COMPUTE

    // reduce over the 16 column-lanes (sum over m within subtile columns)
#pragma unroll
    for (int r = 0; r < 4; ++r) {
        float v0 = g0[r], v1 = g1[r];
        v0 += __shfl_xor(v0, 1); v1 += __shfl_xor(v1, 1);
        v0 += __shfl_xor(v0, 2); v1 += __shfl_xor(v1, 2);
        v0 += __shfl_xor(v0, 4); v1 += __shfl_xor(v1, 4);
        v0 += __shfl_xor(v0, 8); v1 += __shfl_xor(v1, 8);
        g0[r] = v0; g1[r] = v1;
    }

    // each b owned by exactly one wave -> write gs directly (no cross-wave sum)
    if (col == 0) {
#pragma unroll
        for (int r = 0; r < 4; ++r) {
            gs[(wave * 2 + 0) * 16 + quad * 4 + r] = g0[r];
            gs[(wave * 2 + 1) * 16 + quad * 4 + r] = g1[r];
        }
    }
    __syncthreads();

    // epilogue: out[n,o] += sum_{b<127} gs[b]*L2[b,o]   (plain rmw, single writer)
    int o = tid & 127;
    int hf = tid >> 7;
    float acc = 0.f;
    int blo = hf * 64, bhi = hf ? 127 : 64;
#pragma unroll 8
    for (int b = blo; b < bhi; ++b)
        acc += gs[b] * L2[b * OUT_CH + o];   // gs[b] is an LDS broadcast (free)
    part[hf][o] = acc;
    __syncthreads();
    if (tid < 128) {
        size_t idx = (size_t)n * OUT_CH + tid;
        out[idx] += part[0][tid] + part[1][tid];
    }
}

extern "C" void kernel_launch(void* const* d_in, const int* in_sizes, int n_in,
                              void* d_out, int out_size, void* d_ws, size_t ws_size,
                              hipStream_t stream) {
    const float* node_mat    = (const float*)d_in[0];
    const float* adj         = (const float*)d_in[1];
    const float* edge_adj    = (const float*)d_in[2];
    const float* node_weight = (const float*)d_in[3];
    const float* edge_lay_1  = (const float*)d_in[4];
    const float* edge_lay_2  = (const float*)d_in[5];
    const float* root        = (const float*)d_in[6];
    const float* bias        = (const float*)d_in[7];
    float* out = (float*)d_out;

    short* PT = (short*)d_ws;                       // 128*1024 bf16 = 256 KB
    float* R  = (float*)((char*)d_ws + OUT_CH * NN * sizeof(short));  // 512 KB

    node_gemm_kernel<<<NN / 2, 256, 0, stream>>>(node_mat, node_weight, root, PT, R);
    adjp_kernel<<<128, 256, 0, stream>>>(adj, PT, R, bias, out);   // writes base
    edge_out_kernel<<<NN, 256, 0, stream>>>(edge_adj, adj, edge_lay_1,
                                            edge_lay_2, out);      // plain +=
}

// Round 7
// 247.004 us; speedup vs baseline: 1.5841x; 1.1091x over previous
//
#include <hip/hip_runtime.h>
#include <hip/hip_bf16.h>

#define NN 1024
#define IN_CH 128
#define EDGE_CH 32
#define OUT_CH 128
#define NNSQ ((size_t)NN * (size_t)NN)

typedef __attribute__((ext_vector_type(8))) short bf16x8;
typedef __attribute__((ext_vector_type(4))) float f32x4;

// round-to-nearest-even float -> bf16 (bit trick)
static __device__ __forceinline__ short f2bf(float f) {
    union { float f; unsigned u; } v; v.f = f;
    unsigned r = v.u + 0x7FFFu + ((v.u >> 16) & 1u);
    return (short)(r >> 16);
}

// ---------------------------------------------------------------------------
// Kernel A: P = node_mat @ node_weight (stored TRANSPOSED, bf16: PT[o][m]),
//           R = node_mat @ root (fp32).  (unchanged)
// ---------------------------------------------------------------------------
__global__ void node_gemm_kernel(const float* __restrict__ node_mat,
                                 const float* __restrict__ node_weight,
                                 const float* __restrict__ root,
                                 short* __restrict__ PT,
                                 float* __restrict__ R) {
    __shared__ float nm[2 * IN_CH];
    int tid = threadIdx.x;
    int n0 = blockIdx.x * 2;
    nm[tid] = node_mat[n0 * IN_CH + tid];
    __syncthreads();
    int o = tid & 127;
    int h = tid >> 7;
    const float* nr = &nm[h * IN_CH];
    float accp = 0.f, accr = 0.f;
#pragma unroll 8
    for (int c = 0; c < IN_CH; ++c) {
        float x = nr[c];
        accp += x * node_weight[c * OUT_CH + o];
        accr += x * root[c * OUT_CH + o];
    }
    R[(size_t)(n0 + h) * OUT_CH + o] = accr;
    PT[(size_t)o * NN + (n0 + h)] = f2bf(accp);  // transposed bf16 store
}

// ---------------------------------------------------------------------------
// Kernel C (runs before edge_out): out = adj @ P + R + bias  (WRITE mode).
// grid 128 = 64 n-tiles x 2 o-halves; waves split K=1024 into 4 x 256,
// reduce through padded LDS, coalesced write. (unchanged)
// ---------------------------------------------------------------------------
__global__ void adjp_kernel(const float* __restrict__ adj,
                            const short* __restrict__ PT,
                            const float* __restrict__ R,
                            const float* __restrict__ bias,
                            float* __restrict__ out) {
    int blk = blockIdx.x;
    int nb = blk & 63;          // n-tile: 16 rows
    int oh = blk >> 6;          // o-half: 64 cols
    int tid = threadIdx.x;
    int wave = tid >> 6;
    int lane = tid & 63;
    int quad = lane >> 4;
    int col  = lane & 15;
    int n0 = nb * 16;
    int o0 = oh * 64;

    f32x4 acc[4];
#pragma unroll
    for (int ot = 0; ot < 4; ++ot) acc[ot] = (f32x4){0.f, 0.f, 0.f, 0.f};

    int kbase = wave * 256;     // wave-level K-split, reduced in LDS below
#pragma unroll
    for (int ks = 0; ks < 8; ++ks) {
        int k = kbase + ks * 32 + quad * 8;
        const float* ap = adj + (size_t)(n0 + col) * NN + k;
        f32x4 a0 = *(const f32x4*)ap;
        f32x4 a1 = *(const f32x4*)(ap + 4);
        bf16x8 a;
#pragma unroll
        for (int j = 0; j < 4; ++j) { a[j] = f2bf(a0[j]); a[4 + j] = f2bf(a1[j]); }
#pragma unroll
        for (int ot = 0; ot < 4; ++ot) {
            int o = o0 + ot * 16 + col;
            bf16x8 b = *(const bf16x8*)(PT + (size_t)o * NN + k);
            acc[ot] = __builtin_amdgcn_mfma_f32_16x16x32_bf16(a, b, acc[ot], 0, 0, 0);
        }
    }

    __shared__ float red[4][16][65];
#pragma unroll
    for (int ot = 0; ot < 4; ++ot)
#pragma unroll
        for (int r = 0; r < 4; ++r)
            red[wave][quad * 4 + r][ot * 16 + col] = acc[ot][r];
    __syncthreads();

#pragma unroll
    for (int i = tid; i < 16 * 64; i += 256) {
        int rr = i >> 6;
        int cc = i & 63;
        float v = red[0][rr][cc] + red[1][rr][cc] + red[2][rr][cc] + red[3][rr][cc];
        size_t idx = (size_t)(n0 + rr) * OUT_CH + o0 + cc;
        out[idx] = v + R[idx] + bias[o0 + cc];
    }
}

// ---------------------------------------------------------------------------
// Kernel B v6 (heavy): per node n,
//   G[b]  = sum_m adj[n,m] * relu( sum_e edge_adj[e,n,m] * L1[e,b] )
//   out[n,o] += sum_{b<127} G[b]*L2[b,o]            (base pre-written by adjp)
//
// v5 post-mortem: WRITE_SIZE 68 MB = staging regs STILL spilled, because the
// allocator caps at 64 VGPR (max-occupancy heuristic) when no launch bounds
// are given -- LDS already limits us to 3 blocks/CU, so the cap bought
// nothing. v6:
//   - __launch_bounds__(256, 3): VGPR budget ~170/wave at the SAME occupancy
//     -> staging lives in registers (the decisive fix).
//   - 2-deep prefetch, two NAMED register banks stA0-7/stB0-7, 4-chunk
//     schedule fully unrolled (all indices static; rule #20):
//       pro: ISSUE_A(c0) ISSUE_B(c1) CONVERT_A->buf0 bar
//       it0: ISSUE_A(c2) COMPUTE(buf0,c0) CONVERT_B->buf1 bar
//       it1: ISSUE_B(c3) COMPUTE(buf1,c1) CONVERT_A->buf0 bar
//       it2:             COMPUTE(buf0,c2) CONVERT_B->buf1 bar
//       it3:             COMPUTE(buf1,c3)
//     overlap per load = 2 compute phases (~1200cy) > HBM latency.
//   - geometry unchanged from v5: b-split across waves (wave owns b-tiles
//     {2w,2w+1}, full m); staging = 1 e-plane x 1 KB contiguous m per instr;
//     chunk 256m x 32e; LDS transposed [m][40 shorts]; chunk order rotated
//     by n&3 for channel spread.
// MFMA 16x16x32 bf16: A-frag = L1^T [b=bt*16+col][e=quad*8+j] (constant);
// B-frag = one ds_read_b128 [m=st*16+col][e=quad*8+j]; D row=quad*4+r (b).
// ---------------------------------------------------------------------------
__global__ void __launch_bounds__(256, 3)
edge_out_kernel(const float* __restrict__ edge_adj,
                const float* __restrict__ adj,
                const float* __restrict__ L1,
                const float* __restrict__ L2,
                float* __restrict__ out) {
    int n = blockIdx.x;
    int tid = threadIdx.x;
    int wave = tid >> 6;
    int lane = tid & 63;
    int quad = lane >> 4;
    int col  = lane & 15;

    // double-buffered transposed chunk: [256 m][40 shorts] = 20 KB each
    __shared__ __attribute__((aligned(16))) short ea_lds[2][256 * 40];  // 40 KB
    __shared__ float adj_lds[NN];                                       // 4 KB
    __shared__ float gs[OUT_CH];
    __shared__ float part[2][OUT_CH];

    // stage the adj row once (coalesced, 4 KB)
    *(f32x4*)&adj_lds[tid * 4] = *(const f32x4*)(adj + (size_t)n * NN + tid * 4);

    // A fragments: this wave's two b-tiles of L1^T [b][e=quad*8+j]
    bf16x8 a_frag0, a_frag1;
#pragma unroll
    for (int j = 0; j < 8; ++j) {
        int e = quad * 8 + j;
        int b0 = (wave * 2 + 0) * 16 + col;
        int b1 = (wave * 2 + 1) * 16 + col;
        a_frag0[j] = f2bf((b0 < OUT_CH - 1) ? L1[e * (OUT_CH - 1) + b0] : 0.0f);
        a_frag1[j] = f2bf((b1 < OUT_CH - 1) ? L1[e * (OUT_CH - 1) + b1] : 0.0f);
    }

    float g0[4] = {0.f, 0.f, 0.f, 0.f};
    float g1[4] = {0.f, 0.f, 0.f, 0.f};

    // staging base: this wave's 8 e-planes, this n's row, lane covers 4 m
    const float* ea_b = edge_adj + (size_t)(wave * 8) * NNSQ + (size_t)n * NN + lane * 4;

    f32x4 stA0, stA1, stA2, stA3, stA4, stA5, stA6, stA7;   // bank A
    f32x4 stB0, stB1, stB2, stB3, stB4, stB5, stB6, stB7;   // bank B

#define ISSUE_A(AC) { \
        const float* p_ = ea_b + (AC) * 256; \
        stA0 = *(const f32x4*)(p_ + 0 * NNSQ); stA1 = *(const f32x4*)(p_ + 1 * NNSQ); \
        stA2 = *(const f32x4*)(p_ + 2 * NNSQ); stA3 = *(const f32x4*)(p_ + 3 * NNSQ); \
        stA4 = *(const f32x4*)(p_ + 4 * NNSQ); stA5 = *(const f32x4*)(p_ + 5 * NNSQ); \
        stA6 = *(const f32x4*)(p_ + 6 * NNSQ); stA7 = *(const f32x4*)(p_ + 7 * NNSQ); }
#define ISSUE_B(AC) { \
        const float* p_ = ea_b + (AC) * 256; \
        stB0 = *(const f32x4*)(p_ + 0 * NNSQ); stB1 = *(const f32x4*)(p_ + 1 * NNSQ); \
        stB2 = *(const f32x4*)(p_ + 2 * NNSQ); stB3 = *(const f32x4*)(p_ + 3 * NNSQ); \
        stB4 = *(const f32x4*)(p_ + 4 * NNSQ); stB5 = *(const f32x4*)(p_ + 5 * NNSQ); \
        stB6 = *(const f32x4*)(p_ + 6 * NNSQ); stB7 = *(const f32x4*)(p_ + 7 * NNSQ); }
// lane holds 8e x 4m block; write 4 rows of 8 bf16 (16 B) = 4x ds_write_b128
#define CONVERT_A(BUF) { \
        _Pragma("unroll") for (int k = 0; k < 4; ++k) { \
            bf16x8 pk_; \
            pk_[0] = f2bf(stA0[k]); pk_[1] = f2bf(stA1[k]); \
            pk_[2] = f2bf(stA2[k]); pk_[3] = f2bf(stA3[k]); \
            pk_[4] = f2bf(stA4[k]); pk_[5] = f2bf(stA5[k]); \
            pk_[6] = f2bf(stA6[k]); pk_[7] = f2bf(stA7[k]); \
            *(bf16x8*)((BUF) + (lane * 4 + k) * 40 + wave * 8) = pk_; } }
#define CONVERT_B(BUF) { \
        _Pragma("unroll") for (int k = 0; k < 4; ++k) { \
            bf16x8 pk_; \
            pk_[0] = f2bf(stB0[k]); pk_[1] = f2bf(stB1[k]); \
            pk_[2] = f2bf(stB2[k]); pk_[3] = f2bf(stB3[k]); \
            pk_[4] = f2bf(stB4[k]); pk_[5] = f2bf(stB5[k]); \
            pk_[6] = f2bf(stB6[k]); pk_[7] = f2bf(stB7[k]); \
            *(bf16x8*)((BUF) + (lane * 4 + k) * 40 + wave * 8) = pk_; } }
#define COMPUTE(BUF, AC) { \
        _Pragma("unroll") for (int st = 0; st < 16; ++st) { \
            int mrow = st * 16 + col; \
            float adjv = adj_lds[(AC) * 256 + mrow]; \
            bf16x8 bfv = *(const bf16x8*)((BUF) + mrow * 40 + quad * 8); \
            f32x4 d0 = __builtin_amdgcn_mfma_f32_16x16x32_bf16( \
                a_frag0, bfv, (f32x4){0.f, 0.f, 0.f, 0.f}, 0, 0, 0); \
            f32x4 d1 = __builtin_amdgcn_mfma_f32_16x16x32_bf16( \
                a_frag1, bfv, (f32x4){0.f, 0.f, 0.f, 0.f}, 0, 0, 0); \
            _Pragma("unroll") for (int r = 0; r < 4; ++r) { \
                g0[r] += fmaxf(d0[r], 0.0f) * adjv; \
                g1[r] += fmaxf(d1[r], 0.0f) * adjv; } } }

    const int c0 = n & 3, c1 = (n + 1) & 3, c2 = (n + 2) & 3, c3 = (n + 3) & 3;
    short* buf0 = &ea_lds[0][0];
    short* buf1 = &ea_lds[1][0];

    // fully-unrolled 2-deep schedule (all register indices static)
    ISSUE_A(c0); ISSUE_B(c1);
    CONVERT_A(buf0);
    __syncthreads();

    ISSUE_A(c2);
    COMPUTE(buf0, c0);
    CONVERT_B(buf1);
    __syncthreads();

    ISSUE_B(c3);
    COMPUTE(buf1, c1);
    CONVERT_A(buf0);
    __syncthreads();

    COMPUTE(buf0, c2);
    CONVERT_B(buf1);
    __syncthreads();

    COMPUTE(buf1, c3);

#undef ISSUE_A
#undef ISSUE_B
#undef CONVERT_A
#undef CONVERT_B
#undef COMPUTE

    // reduce over the 16 column-lanes (sum over m within subtile columns)
#pragma unroll
    for (int r = 0; r < 4; ++r) {
        float v0 = g0[r], v1 = g1[r];
        v0 += __shfl_xor(v0, 1); v1 += __shfl_xor(v1, 1);
        v0 += __shfl_xor(v0, 2); v1 += __shfl_xor(v1, 2);
        v0 += __shfl_xor(v0, 4); v1 += __shfl_xor(v1, 4);
        v0 += __shfl_xor(v0, 8); v1 += __shfl_xor(v1, 8);
        g0[r] = v0; g1[r] = v1;
    }

    // each b owned by exactly one wave -> write gs directly (no cross-wave sum)
    if (col == 0) {
#pragma unroll
        for (int r = 0; r < 4; ++r) {
            gs[(wave * 2 + 0) * 16 + quad * 4 + r] = g0[r];
            gs[(wave * 2 + 1) * 16 + quad * 4 + r] = g1[r];
        }
    }
    __syncthreads();

    // epilogue: out[n,o] += sum_{b<127} gs[b]*L2[b,o]   (plain rmw, single writer)
    int o = tid & 127;
    int hf = tid >> 7;
    float acc = 0.f;
    int blo = hf * 64, bhi = hf ? 127 : 64;
#pragma unroll 8
    for (int b = blo; b < bhi; ++b)
        acc += gs[b] * L2[b * OUT_CH + o];   // gs[b] is an LDS broadcast (free)
    part[hf][o] = acc;
    __syncthreads();
    if (tid < 128) {
        size_t idx = (size_t)n * OUT_CH + tid;
        out[idx] += part[0][tid] + part[1][tid];
    }
}

extern "C" void kernel_launch(void* const* d_in, const int* in_sizes, int n_in,
                              void* d_out, int out_size, void* d_ws, size_t ws_size,
                              hipStream_t stream) {
    const float* node_mat    = (const float*)d_in[0];
    const float* adj         = (const float*)d_in[1];
    const float* edge_adj    = (const float*)d_in[2];
    const float* node_weight = (const float*)d_in[3];
    const float* edge_lay_1  = (const float*)d_in[4];
    const float* edge_lay_2  = (const float*)d_in[5];
    const float* root        = (const float*)d_in[6];
    const float* bias        = (const float*)d_in[7];
    float* out = (float*)d_out;

    short* PT = (short*)d_ws;                       // 128*1024 bf16 = 256 KB
    float* R  = (float*)((char*)d_ws + OUT_CH * NN * sizeof(short));  // 512 KB

    node_gemm_kernel<<<NN / 2, 256, 0, stream>>>(node_mat, node_weight, root, PT, R);
    adjp_kernel<<<128, 256, 0, stream>>>(adj, PT, R, bias, out);   // writes base
    edge_out_kernel<<<NN, 256, 0, stream>>>(edge_adj, adj, edge_lay_1,
                                            edge_lay_2, out);      // plain +=
}

// Round 8
// 238.151 us; speedup vs baseline: 1.6430x; 1.0372x over previous
//
#include <hip/hip_runtime.h>
#include <hip/hip_bf16.h>

#define NN 1024
#define IN_CH 128
#define EDGE_CH 32
#define OUT_CH 128
#define NNSQ ((size_t)NN * (size_t)NN)

typedef __attribute__((ext_vector_type(8))) short bf16x8;
typedef __attribute__((ext_vector_type(4))) float f32x4;

// round-to-nearest-even float -> bf16 (bit trick)
static __device__ __forceinline__ short f2bf(float f) {
    union { float f; unsigned u; } v; v.f = f;
    unsigned r = v.u + 0x7FFFu + ((v.u >> 16) & 1u);
    return (short)(r >> 16);
}

// ---------------------------------------------------------------------------
// Kernel A: P = node_mat @ node_weight (stored TRANSPOSED, bf16: PT[o][m]),
//           R = node_mat @ root (fp32).  (unchanged)
// ---------------------------------------------------------------------------
__global__ void node_gemm_kernel(const float* __restrict__ node_mat,
                                 const float* __restrict__ node_weight,
                                 const float* __restrict__ root,
                                 short* __restrict__ PT,
                                 float* __restrict__ R) {
    __shared__ float nm[2 * IN_CH];
    int tid = threadIdx.x;
    int n0 = blockIdx.x * 2;
    nm[tid] = node_mat[n0 * IN_CH + tid];
    __syncthreads();
    int o = tid & 127;
    int h = tid >> 7;
    const float* nr = &nm[h * IN_CH];
    float accp = 0.f, accr = 0.f;
#pragma unroll 8
    for (int c = 0; c < IN_CH; ++c) {
        float x = nr[c];
        accp += x * node_weight[c * OUT_CH + o];
        accr += x * root[c * OUT_CH + o];
    }
    R[(size_t)(n0 + h) * OUT_CH + o] = accr;
    PT[(size_t)o * NN + (n0 + h)] = f2bf(accp);  // transposed bf16 store
}

// ---------------------------------------------------------------------------
// Kernel C (runs before edge_out): out = adj @ P + R + bias  (WRITE mode).
// (unchanged)
// ---------------------------------------------------------------------------
__global__ void adjp_kernel(const float* __restrict__ adj,
                            const short* __restrict__ PT,
                            const float* __restrict__ R,
                            const float* __restrict__ bias,
                            float* __restrict__ out) {
    int blk = blockIdx.x;
    int nb = blk & 63;          // n-tile: 16 rows
    int oh = blk >> 6;          // o-half: 64 cols
    int tid = threadIdx.x;
    int wave = tid >> 6;
    int lane = tid & 63;
    int quad = lane >> 4;
    int col  = lane & 15;
    int n0 = nb * 16;
    int o0 = oh * 64;

    f32x4 acc[4];
#pragma unroll
    for (int ot = 0; ot < 4; ++ot) acc[ot] = (f32x4){0.f, 0.f, 0.f, 0.f};

    int kbase = wave * 256;     // wave-level K-split, reduced in LDS below
#pragma unroll
    for (int ks = 0; ks < 8; ++ks) {
        int k = kbase + ks * 32 + quad * 8;
        const float* ap = adj + (size_t)(n0 + col) * NN + k;
        f32x4 a0 = *(const f32x4*)ap;
        f32x4 a1 = *(const f32x4*)(ap + 4);
        bf16x8 a;
#pragma unroll
        for (int j = 0; j < 4; ++j) { a[j] = f2bf(a0[j]); a[4 + j] = f2bf(a1[j]); }
#pragma unroll
        for (int ot = 0; ot < 4; ++ot) {
            int o = o0 + ot * 16 + col;
            bf16x8 b = *(const bf16x8*)(PT + (size_t)o * NN + k);
            acc[ot] = __builtin_amdgcn_mfma_f32_16x16x32_bf16(a, b, acc[ot], 0, 0, 0);
        }
    }

    __shared__ float red[4][16][65];
#pragma unroll
    for (int ot = 0; ot < 4; ++ot)
#pragma unroll
        for (int r = 0; r < 4; ++r)
            red[wave][quad * 4 + r][ot * 16 + col] = acc[ot][r];
    __syncthreads();

#pragma unroll
    for (int i = tid; i < 16 * 64; i += 256) {
        int rr = i >> 6;
        int cc = i & 63;
        float v = red[0][rr][cc] + red[1][rr][cc] + red[2][rr][cc] + red[3][rr][cc];
        size_t idx = (size_t)(n0 + rr) * OUT_CH + o0 + cc;
        out[idx] = v + R[idx] + bias[o0 + cc];
    }
}

// ---------------------------------------------------------------------------
// Kernel B v7 (heavy): identical structure to v6 (spill-free, 2-deep
// prefetch, launch_bounds(256,3)) with ONE change: edge_adj staging loads
// are NON-TEMPORAL (__builtin_nontemporal_load).
//
// v6 post-mortem: spills eliminated (WRITE 68->2.5 MB) yet dur unchanged at
// ~80 us / ~1.7 TB/s demand. Four structurally different kernels (r0 scalar
// gather, v2 lockstep, v5, v6) ALL cap at ~1.7 TB/s for this access shape
// (4-KB row x 32 e-planes at 4-MiB stride). L3 serves ~half the stream with
// ZERO speedup -> memory-side cache hits don't help -> suspect serialization
// in the L2/L3 allocation path for 4-MiB-strided lines. nt loads bypass
// cache allocation: if the serializer is there, this breaks the cap; if the
// cap is in the channel mapping itself, this is null and we are at the
// pattern roofline.
// ---------------------------------------------------------------------------
__global__ void __launch_bounds__(256, 3)
edge_out_kernel(const float* __restrict__ edge_adj,
                const float* __restrict__ adj,
                const float* __restrict__ L1,
                const float* __restrict__ L2,
                float* __restrict__ out) {
    int n = blockIdx.x;
    int tid = threadIdx.x;
    int wave = tid >> 6;
    int lane = tid & 63;
    int quad = lane >> 4;
    int col  = lane & 15;

    // double-buffered transposed chunk: [256 m][40 shorts] = 20 KB each
    __shared__ __attribute__((aligned(16))) short ea_lds[2][256 * 40];  // 40 KB
    __shared__ float adj_lds[NN];                                       // 4 KB
    __shared__ float gs[OUT_CH];
    __shared__ float part[2][OUT_CH];

    // stage the adj row once (coalesced, 4 KB)
    *(f32x4*)&adj_lds[tid * 4] = *(const f32x4*)(adj + (size_t)n * NN + tid * 4);

    // A fragments: this wave's two b-tiles of L1^T [b][e=quad*8+j]
    bf16x8 a_frag0, a_frag1;
#pragma unroll
    for (int j = 0; j < 8; ++j) {
        int e = quad * 8 + j;
        int b0 = (wave * 2 + 0) * 16 + col;
        int b1 = (wave * 2 + 1) * 16 + col;
        a_frag0[j] = f2bf((b0 < OUT_CH - 1) ? L1[e * (OUT_CH - 1) + b0] : 0.0f);
        a_frag1[j] = f2bf((b1 < OUT_CH - 1) ? L1[e * (OUT_CH - 1) + b1] : 0.0f);
    }

    float g0[4] = {0.f, 0.f, 0.f, 0.f};
    float g1[4] = {0.f, 0.f, 0.f, 0.f};

    // staging base: this wave's 8 e-planes, this n's row, lane covers 4 m
    const float* ea_b = edge_adj + (size_t)(wave * 8) * NNSQ + (size_t)n * NN + lane * 4;

    f32x4 stA0, stA1, stA2, stA3, stA4, stA5, stA6, stA7;   // bank A
    f32x4 stB0, stB1, stB2, stB3, stB4, stB5, stB6, stB7;   // bank B

#define NTLD(P) __builtin_nontemporal_load((const f32x4*)(P))
#define ISSUE_A(AC) { \
        const float* p_ = ea_b + (AC) * 256; \
        stA0 = NTLD(p_ + 0 * NNSQ); stA1 = NTLD(p_ + 1 * NNSQ); \
        stA2 = NTLD(p_ + 2 * NNSQ); stA3 = NTLD(p_ + 3 * NNSQ); \
        stA4 = NTLD(p_ + 4 * NNSQ); stA5 = NTLD(p_ + 5 * NNSQ); \
        stA6 = NTLD(p_ + 6 * NNSQ); stA7 = NTLD(p_ + 7 * NNSQ); }
#define ISSUE_B(AC) { \
        const float* p_ = ea_b + (AC) * 256; \
        stB0 = NTLD(p_ + 0 * NNSQ); stB1 = NTLD(p_ + 1 * NNSQ); \
        stB2 = NTLD(p_ + 2 * NNSQ); stB3 = NTLD(p_ + 3 * NNSQ); \
        stB4 = NTLD(p_ + 4 * NNSQ); stB5 = NTLD(p_ + 5 * NNSQ); \
        stB6 = NTLD(p_ + 6 * NNSQ); stB7 = NTLD(p_ + 7 * NNSQ); }
// lane holds 8e x 4m block; write 4 rows of 8 bf16 (16 B) = 4x ds_write_b128
#define CONVERT_A(BUF) { \
        _Pragma("unroll") for (int k = 0; k < 4; ++k) { \
            bf16x8 pk_; \
            pk_[0] = f2bf(stA0[k]); pk_[1] = f2bf(stA1[k]); \
            pk_[2] = f2bf(stA2[k]); pk_[3] = f2bf(stA3[k]); \
            pk_[4] = f2bf(stA4[k]); pk_[5] = f2bf(stA5[k]); \
            pk_[6] = f2bf(stA6[k]); pk_[7] = f2bf(stA7[k]); \
            *(bf16x8*)((BUF) + (lane * 4 + k) * 40 + wave * 8) = pk_; } }
#define CONVERT_B(BUF) { \
        _Pragma("unroll") for (int k = 0; k < 4; ++k) { \
            bf16x8 pk_; \
            pk_[0] = f2bf(stB0[k]); pk_[1] = f2bf(stB1[k]); \
            pk_[2] = f2bf(stB2[k]); pk_[3] = f2bf(stB3[k]); \
            pk_[4] = f2bf(stB4[k]); pk_[5] = f2bf(stB5[k]); \
            pk_[6] = f2bf(stB6[k]); pk_[7] = f2bf(stB7[k]); \
            *(bf16x8*)((BUF) + (lane * 4 + k) * 40 + wave * 8) = pk_; } }
#define COMPUTE(BUF, AC) { \
        _Pragma("unroll") for (int st = 0; st < 16; ++st) { \
            int mrow = st * 16 + col; \
            float adjv = adj_lds[(AC) * 256 + mrow]; \
            bf16x8 bfv = *(const bf16x8*)((BUF) + mrow * 40 + quad * 8); \
            f32x4 d0 = __builtin_amdgcn_mfma_f32_16x16x32_bf16( \
                a_frag0, bfv, (f32x4){0.f, 0.f, 0.f, 0.f}, 0, 0, 0); \
            f32x4 d1 = __builtin_amdgcn_mfma_f32_16x16x32_bf16( \
                a_frag1, bfv, (f32x4){0.f, 0.f, 0.f, 0.f}, 0, 0, 0); \
            _Pragma("unroll") for (int r = 0; r < 4; ++r) { \
                g0[r] += fmaxf(d0[r], 0.0f) * adjv; \
                g1[r] += fmaxf(d1[r], 0.0f) * adjv; } } }

    const int c0 = n & 3, c1 = (n + 1) & 3, c2 = (n + 2) & 3, c3 = (n + 3) & 3;
    short* buf0 = &ea_lds[0][0];
    short* buf1 = &ea_lds[1][0];

    // fully-unrolled 2-deep schedule (all register indices static)
    ISSUE_A(c0); ISSUE_B(c1);
    CONVERT_A(buf0);
    __syncthreads();

    ISSUE_A(c2);
    COMPUTE(buf0, c0);
    CONVERT_B(buf1);
    __syncthreads();

    ISSUE_B(c3);
    COMPUTE(buf1, c1);
    CONVERT_A(buf0);
    __syncthreads();

    COMPUTE(buf0, c2);
    CONVERT_B(buf1);
    __syncthreads();

    COMPUTE(buf1, c3);

#undef NTLD
#undef ISSUE_A
#undef ISSUE_B
#undef CONVERT_A
#undef CONVERT_B
#undef COMPUTE

    // reduce over the 16 column-lanes (sum over m within subtile columns)
#pragma unroll
    for (int r = 0; r < 4; ++r) {
        float v0 = g0[r], v1 = g1[r];
        v0 += __shfl_xor(v0, 1); v1 += __shfl_xor(v1, 1);
        v0 += __shfl_xor(v0, 2); v1 += __shfl_xor(v1, 2);
        v0 += __shfl_xor(v0, 4); v1 += __shfl_xor(v1, 4);
        v0 += __shfl_xor(v0, 8); v1 += __shfl_xor(v1, 8);
        g0[r] = v0; g1[r] = v1;
    }

    // each b owned by exactly one wave -> write gs directly (no cross-wave sum)
    if (col == 0) {
#pragma unroll
        for (int r = 0; r < 4; ++r) {
            gs[(wave * 2 + 0) * 16 + quad * 4 + r] = g0[r];
            gs[(wave * 2 + 1) * 16 + quad * 4 + r] = g1[r];
        }
    }
    __syncthreads();

    // epilogue: out[n,o] += sum_{b<127} gs[b]*L2[b,o]   (plain rmw, single writer)
    int o = tid & 127;
    int hf = tid >> 7;
    float acc = 0.f;
    int blo = hf * 64, bhi = hf ? 127 : 64;
#pragma unroll 8
    for (int b = blo; b < bhi; ++b)
        acc += gs[b] * L2[b * OUT_CH + o];   // gs[b] is an LDS broadcast (free)
    part[hf][o] = acc;
    __syncthreads();
    if (tid < 128) {
        size_t idx = (size_t)n * OUT_CH + tid;
        out[idx] += part[0][tid] + part[1][tid];
    }
}

extern "C" void kernel_launch(void* const* d_in, const int* in_sizes, int n_in,
                              void* d_out, int out_size, void* d_ws, size_t ws_size,
                              hipStream_t stream) {
    const float* node_mat    = (const float*)d_in[0];
    const float* adj         = (const float*)d_in[1];
    const float* edge_adj    = (const float*)d_in[2];
    const float* node_weight = (const float*)d_in[3];
    const float* edge_lay_1  = (const float*)d_in[4];
    const float* edge_lay_2  = (const float*)d_in[5];
    const float* root        = (const float*)d_in[6];
    const float* bias        = (const float*)d_in[7];
    float* out = (float*)d_out;

    short* PT = (short*)d_ws;                       // 128*1024 bf16 = 256 KB
    float* R  = (float*)((char*)d_ws + OUT_CH * NN * sizeof(short));  // 512 KB

    node_gemm_kernel<<<NN / 2, 256, 0, stream>>>(node_mat, node_weight, root, PT, R);
    adjp_kernel<<<128, 256, 0, stream>>>(adj, PT, R, bias, out);   // writes base
    edge_out_kernel<<<NN, 256, 0, stream>>>(edge_adj, adj, edge_lay_1,
                                            edge_lay_2, out);      // plain +=
}